// Round 1
// baseline (442.642 us; speedup 1.0000x reference)
//
#include <hip/hip_runtime.h>

#define BOX   256
#define NCLS  2
#define BATCH 2
#define NPTS  262144          // 2^18
#define VOL   (BOX * BOX * BOX)

__global__ __launch_bounds__(256) void cic_scatter_kernel(
    const float* __restrict__ points,   // [B, N, 3]
    const float* __restrict__ values,   // [B, C, N]
    float* __restrict__ out)            // [B, C, V]
{
    const int tid = blockIdx.x * blockDim.x + threadIdx.x;
    const int total = BATCH * NPTS;
    if (tid >= total) return;

    const int b = tid >> 18;            // NPTS = 2^18
    const int n = tid & (NPTS - 1);

    // ---- load point (3 consecutive floats; adjacent threads are ~coalesced)
    const float* pp = points + ((size_t)b * NPTS + n) * 3;
    const float px = (pp[0] + 0.5f) * (float)BOX;
    const float py = (pp[1] + 0.5f) * (float)BOX;
    const float pz = (pp[2] + 0.5f) * (float)BOX;

    const float fx = floorf(px), fy = floorf(py), fz = floorf(pz);
    const float rx = px - fx,    ry = py - fy,    rz = pz - fz;
    const int   ix = (int)fx,    iy = (int)fy,    iz = (int)fz;

    // ---- per-class values (coalesced: stride-1 in n)
    const float v0 = values[((size_t)b * NCLS + 0) * NPTS + n];
    const float v1 = values[((size_t)b * NCLS + 1) * NPTS + n];

    const float wx[2] = {1.0f - rx, rx};
    const float wy[2] = {1.0f - ry, ry};
    const float wz[2] = {1.0f - rz, rz};

    float* __restrict__ out0 = out + ((size_t)b * NCLS + 0) * (size_t)VOL;
    float* __restrict__ out1 = out + ((size_t)b * NCLS + 1) * (size_t)VOL;

    // 8 corners; out-of-range corners in the reference get weight 0, so
    // skipping them is bit-identical (they contribute exactly +0).
#pragma unroll
    for (int dz = 0; dz < 2; ++dz) {
        const int z = iz + dz;
        if (z < 0 || z >= BOX) continue;
#pragma unroll
        for (int dy = 0; dy < 2; ++dy) {
            const int y = iy + dy;
            if (y < 0 || y >= BOX) continue;
            const float wzy = wz[dz] * wy[dy];
            const int rowbase = (z * BOX + y) * BOX;
#pragma unroll
            for (int dx = 0; dx < 2; ++dx) {
                const int x = ix + dx;
                if (x < 0 || x >= BOX) continue;
                const float w = wzy * wx[dx];
                const int idx = rowbase + x;
                atomicAdd(out0 + idx, w * v0);
                atomicAdd(out1 + idx, w * v1);
            }
        }
    }
}

extern "C" void kernel_launch(void* const* d_in, const int* in_sizes, int n_in,
                              void* d_out, int out_size, void* d_ws, size_t ws_size,
                              hipStream_t stream) {
    const float* points = (const float*)d_in[0];   // [B, N, 3]
    const float* values = (const float*)d_in[1];   // [B, C, N]
    float* out = (float*)d_out;                    // [B, C, 256,256,256]

    // Zero the output volume (268 MB) — contributions are sparse.
    hipMemsetAsync(out, 0, (size_t)out_size * sizeof(float), stream);

    const int total = BATCH * NPTS;
    const int block = 256;
    const int grid = (total + block - 1) / block;
    cic_scatter_kernel<<<grid, block, 0, stream>>>(points, values, out);
}

// Round 2
// 143.080 us; speedup vs baseline: 3.0937x; 3.0937x over previous
//
#include <hip/hip_runtime.h>

#define BOX   256
#define NCLS  2
#define BATCH 2
#define NPTS  262144                      // 2^18
#define VOL   (BOX * BOX * BOX)
#define NBINS (BATCH * BOX * BOX)         // bins keyed by (b, base_z, base_y) = 131072
#define RY    32                          // rows per region tile
#define NT    (BOX / RY)                  // 8 y-tiles per plane
#define NREG  (BATCH * BOX * NT)          // 4096 regions

// ---------------------------------------------------------------------------
// Pass 1: count points per (b, base_z, base_y) row-bin
// ---------------------------------------------------------------------------
__global__ __launch_bounds__(256) void k_count(const float* __restrict__ pts,
                                               unsigned* __restrict__ count)
{
    const int tid = blockIdx.x * 256 + threadIdx.x;       // exactly BATCH*NPTS threads
    const int b = tid >> 18;
    const int n = tid & (NPTS - 1);
    const float* pp = pts + ((size_t)b * NPTS + n) * 3;
    const float py = (pp[1] + 0.5f) * (float)BOX;
    const float pz = (pp[2] + 0.5f) * (float)BOX;
    const int by = (int)floorf(py);
    const int bz = (int)floorf(pz);
    const int bin = (((b << 8) | bz) << 8) | by;
    atomicAdd(&count[bin], 1u);
}

// ---------------------------------------------------------------------------
// Pass 2: per-block scan of counts; block base via one atomic on a global total.
// start[] offsets are unique (cross-block order is arbitrary but irrelevant:
// region pass reads per-bin (start,count) pairs, never assumes global order).
// ---------------------------------------------------------------------------
__global__ __launch_bounds__(1024) void k_scan(const unsigned* __restrict__ count,
                                               unsigned* __restrict__ start,
                                               unsigned* __restrict__ cursor,
                                               unsigned* __restrict__ total)
{
    __shared__ unsigned s[1024];
    __shared__ unsigned base;
    const int i = blockIdx.x * 1024 + threadIdx.x;
    const unsigned v = count[i];
    s[threadIdx.x] = v;
    __syncthreads();
    for (int off = 1; off < 1024; off <<= 1) {
        unsigned t = 0;
        if ((int)threadIdx.x >= off) t = s[threadIdx.x - off];
        __syncthreads();
        if ((int)threadIdx.x >= off) s[threadIdx.x] += t;
        __syncthreads();
    }
    const unsigned incl = s[threadIdx.x];
    if (threadIdx.x == 1023) base = atomicAdd(total, incl);
    __syncthreads();
    const unsigned st = base + incl - v;   // exclusive within block + block base
    start[i]  = st;
    cursor[i] = st;
}

// ---------------------------------------------------------------------------
// Pass 3: compact records into binned order. rec4 = {px,py,pz,v0}, recv = v1.
// ---------------------------------------------------------------------------
__global__ __launch_bounds__(256) void k_place(const float* __restrict__ pts,
                                               const float* __restrict__ vals,
                                               unsigned* __restrict__ cursor,
                                               float4* __restrict__ rec4,
                                               float* __restrict__ recv)
{
    const int tid = blockIdx.x * 256 + threadIdx.x;
    const int b = tid >> 18;
    const int n = tid & (NPTS - 1);
    const float* pp = pts + ((size_t)b * NPTS + n) * 3;
    const float px = (pp[0] + 0.5f) * (float)BOX;
    const float py = (pp[1] + 0.5f) * (float)BOX;
    const float pz = (pp[2] + 0.5f) * (float)BOX;
    const int by = (int)floorf(py);
    const int bz = (int)floorf(pz);
    const int bin = (((b << 8) | bz) << 8) | by;
    const unsigned slot = atomicAdd(&cursor[bin], 1u);
    const float v0 = vals[((size_t)b * NCLS + 0) * NPTS + n];
    const float v1 = vals[((size_t)b * NCLS + 1) * NPTS + n];
    rec4[slot] = make_float4(px, py, pz, v0);
    recv[slot] = v1;
}

// ---------------------------------------------------------------------------
// Pass 4: one block per (b, z-plane P, y-tile T). Accumulate contributing
// records into a 64 KB LDS tile (2 classes x 32 rows x 256 x) with LDS
// atomics, then stream the tile out with coalesced float4 stores.
// Every voxel is written exactly once -> no global memset needed.
// ---------------------------------------------------------------------------
__global__ __launch_bounds__(1024) void k_region(const float4* __restrict__ rec4,
                                                 const float* __restrict__ recv,
                                                 const unsigned* __restrict__ start,
                                                 const unsigned* __restrict__ count,
                                                 float* __restrict__ out)
{
    __shared__ float acc[NCLS * RY * BOX];          // 64 KB
    __shared__ unsigned s_start[66];
    __shared__ unsigned s_len[66];
    __shared__ unsigned s_pfx[67];

    const int bid = blockIdx.x;
    const int b = bid >> 11;
    const int P = (bid >> 3) & 255;                 // owned z-plane
    const int T = bid & 7;                          // owned y-tile (rows RY*T .. RY*T+31)

    // zero the LDS tile (vectorized)
    {
        float4* a4 = (float4*)acc;
        #pragma unroll
        for (int i = 0; i < 4; ++i)
            a4[i * 1024 + threadIdx.x] = make_float4(0.f, 0.f, 0.f, 0.f);
    }

    // bin metadata: 2 source planes (P-1, P) x 33 rows (RY*T-1 .. RY*T+31)
    if (threadIdx.x < 66) {
        const int j = threadIdx.x;
        const int zsrc = P - 1 + (j / 33);
        const int y0 = RY * T - 1 + (j % 33);
        unsigned len = 0, st = 0;
        if (zsrc >= 0 && y0 >= 0 && y0 < BOX) {
            const int bin = (((b << 8) | zsrc) << 8) | y0;
            len = count[bin];
            st = start[bin];
        }
        s_start[j] = st;
        s_len[j] = len;
    }
    __syncthreads();
    if (threadIdx.x == 0) {
        unsigned run = 0;
        for (int j = 0; j < 66; ++j) { s_pfx[j] = run; run += s_len[j]; }
        s_pfx[66] = run;
    }
    __syncthreads();

    const int R = (int)s_pfx[66];
    for (int r = threadIdx.x; r < R; r += 1024) {
        // binary search: j with s_pfx[j] <= r < s_pfx[j+1]
        int lo = 0, hi = 65;
        while (lo < hi) {
            const int mid = (lo + hi + 1) >> 1;
            if ((int)s_pfx[mid] <= r) lo = mid; else hi = mid - 1;
        }
        const unsigned idx = s_start[lo] + (unsigned)(r - (int)s_pfx[lo]);

        const float4 q = rec4[idx];
        const float v1 = recv[idx];
        const float fx = floorf(q.x), fy = floorf(q.y), fz = floorf(q.z);
        const float rx = q.x - fx, ry = q.y - fy, rz = q.z - fz;
        const int bx = (int)fx, byy = (int)fy, bz = (int)fz;

        // corner on plane P: dz=0 (bz==P) weight (1-rz); dz=1 (bz==P-1) weight rz
        const float wz = (bz == P) ? (1.0f - rz) : rz;

        #pragma unroll
        for (int dy = 0; dy < 2; ++dy) {
            const int y = byy + dy;
            const int yy = y - RY * T;
            if ((unsigned)yy < RY) {                 // also excludes y==256 corner
                const float wzy = wz * (dy ? ry : 1.0f - ry);
                #pragma unroll
                for (int dx = 0; dx < 2; ++dx) {
                    const int x = bx + dx;
                    if (x < BOX) {                   // excludes x==256 corner
                        const float w = wzy * (dx ? rx : 1.0f - rx);
                        const int li = yy * BOX + x;
                        atomicAdd(&acc[li], w * q.w);
                        atomicAdd(&acc[RY * BOX + li], w * v1);
                    }
                }
            }
        }
    }
    __syncthreads();

    // stream tile to global: [b][c][P][RY*T .. RY*T+31][0..255], coalesced float4
    #pragma unroll
    for (int c = 0; c < NCLS; ++c) {
        const size_t obase = (((size_t)(b * NCLS + c) * BOX + P) * (BOX * BOX)
                              + (size_t)RY * T * BOX) >> 2;   // in float4 units
        float4* o4 = (float4*)out;
        const float4* a4 = (const float4*)(acc + c * RY * BOX);
        #pragma unroll
        for (int i = 0; i < 2; ++i)
            o4[obase + i * 1024 + threadIdx.x] = a4[i * 1024 + threadIdx.x];
    }
}

// ---------------------------------------------------------------------------
// Fallback (round-1 kernel): plain global-atomic scatter, used if ws too small.
// ---------------------------------------------------------------------------
__global__ __launch_bounds__(256) void cic_scatter_kernel(
    const float* __restrict__ points, const float* __restrict__ values,
    float* __restrict__ out)
{
    const int tid = blockIdx.x * blockDim.x + threadIdx.x;
    if (tid >= BATCH * NPTS) return;
    const int b = tid >> 18, n = tid & (NPTS - 1);
    const float* pp = points + ((size_t)b * NPTS + n) * 3;
    const float px = (pp[0] + 0.5f) * BOX, py = (pp[1] + 0.5f) * BOX, pz = (pp[2] + 0.5f) * BOX;
    const float fx = floorf(px), fy = floorf(py), fz = floorf(pz);
    const float rx = px - fx, ry = py - fy, rz = pz - fz;
    const int ix = (int)fx, iy = (int)fy, iz = (int)fz;
    const float v0 = values[((size_t)b * NCLS + 0) * NPTS + n];
    const float v1 = values[((size_t)b * NCLS + 1) * NPTS + n];
    const float wx[2] = {1.f - rx, rx}, wy[2] = {1.f - ry, ry}, wz[2] = {1.f - rz, rz};
    float* out0 = out + ((size_t)b * NCLS + 0) * (size_t)VOL;
    float* out1 = out + ((size_t)b * NCLS + 1) * (size_t)VOL;
    for (int dz = 0; dz < 2; ++dz) {
        const int z = iz + dz; if (z >= BOX) continue;
        for (int dy = 0; dy < 2; ++dy) {
            const int y = iy + dy; if (y >= BOX) continue;
            const float wzy = wz[dz] * wy[dy];
            const int rowbase = (z * BOX + y) * BOX;
            for (int dx = 0; dx < 2; ++dx) {
                const int x = ix + dx; if (x >= BOX) continue;
                const float w = wzy * wx[dx];
                atomicAdd(out0 + rowbase + x, w * v0);
                atomicAdd(out1 + rowbase + x, w * v1);
            }
        }
    }
}

extern "C" void kernel_launch(void* const* d_in, const int* in_sizes, int n_in,
                              void* d_out, int out_size, void* d_ws, size_t ws_size,
                              hipStream_t stream) {
    const float* points = (const float*)d_in[0];   // [B, N, 3]
    const float* values = (const float*)d_in[1];   // [B, C, N]
    float* out = (float*)d_out;                    // [B, C, 256,256,256]

    // ws layout
    const size_t CNT_OFF   = 0;
    const size_t TOT_OFF   = (size_t)NBINS * 4;                 // 524288
    const size_t START_OFF = TOT_OFF + 256;                     // padded
    const size_t CUR_OFF   = START_OFF + (size_t)NBINS * 4;
    const size_t REC4_OFF  = CUR_OFF + (size_t)NBINS * 4;       // 16B-aligned
    const size_t RECV_OFF  = REC4_OFF + (size_t)BATCH * NPTS * 16;
    const size_t WS_NEED   = RECV_OFF + (size_t)BATCH * NPTS * 4;

    if (ws_size < WS_NEED) {
        // fallback: zero + global-atomic scatter
        hipMemsetAsync(out, 0, (size_t)out_size * sizeof(float), stream);
        const int total = BATCH * NPTS;
        cic_scatter_kernel<<<(total + 255) / 256, 256, 0, stream>>>(points, values, out);
        return;
    }

    char* ws = (char*)d_ws;
    unsigned* count  = (unsigned*)(ws + CNT_OFF);
    unsigned* total  = (unsigned*)(ws + TOT_OFF);
    unsigned* start  = (unsigned*)(ws + START_OFF);
    unsigned* cursor = (unsigned*)(ws + CUR_OFF);
    float4*   rec4   = (float4*)(ws + REC4_OFF);
    float*    recv   = (float*)(ws + RECV_OFF);

    // zero counters + total (start/cursor fully overwritten by k_scan)
    hipMemsetAsync(ws, 0, TOT_OFF + 256, stream);

    const int npt_blocks = (BATCH * NPTS) / 256;   // 2048
    k_count<<<npt_blocks, 256, 0, stream>>>(points, count);
    k_scan<<<NBINS / 1024, 1024, 0, stream>>>(count, start, cursor, total);
    k_place<<<npt_blocks, 256, 0, stream>>>(points, values, cursor, rec4, recv);
    k_region<<<NREG, 1024, 0, stream>>>(rec4, recv, start, count, out);
}

// Round 3
// 112.772 us; speedup vs baseline: 3.9251x; 1.2688x over previous
//
#include <hip/hip_runtime.h>

#define BOX   256
#define NCLS  2
#define BATCH 2
#define NPTS  262144                      // 2^18
#define VOL   (BOX * BOX * BOX)
#define NBINS (BATCH * BOX * BOX)         // (b, base_z, base_y) row-bins = 131072
#define CAP   32                          // records per bin (Poisson mean 4)
#define CAPSH 5
#define RY    16                          // rows per region tile
#define NT    (BOX / RY)                  // 16 y-tiles per plane
#define NREG  (BATCH * BOX * NT)          // 8192 region blocks
#define NBMETA 34                         // 2 planes x 17 rows per region

// ---------------------------------------------------------------------------
// Pass 1: one atomic per point -> slot in capacity-binned record array.
// Record = {px, pack16(ry,rz), v0, v1} (16 B). Overflow (never for this
// input; P[Poisson(4)>32] ~ 1e-19) goes to a global list, handled correctly.
// ---------------------------------------------------------------------------
__global__ __launch_bounds__(256) void k_place(const float* __restrict__ pts,
                                               const float* __restrict__ vals,
                                               unsigned* __restrict__ cursor,
                                               float4* __restrict__ rec,
                                               float4* __restrict__ ovf4,
                                               unsigned* __restrict__ ovfbin,
                                               unsigned* __restrict__ ovfcnt)
{
    const int tid = blockIdx.x * 256 + threadIdx.x;   // exactly BATCH*NPTS threads
    const int b = tid >> 18;
    const int n = tid & (NPTS - 1);

    const float* pp = pts + ((size_t)b * NPTS + n) * 3;
    const float px = (pp[0] + 0.5f) * (float)BOX;
    const float py = (pp[1] + 0.5f) * (float)BOX;
    const float pz = (pp[2] + 0.5f) * (float)BOX;

    const float fy = floorf(py), fz = floorf(pz);
    const int by = (int)fy, bz = (int)fz;
    const float ry = py - fy, rz = pz - fz;

    // 16-bit fixed-point fractions (error <= 2^-16 per weight)
    const unsigned qy = (unsigned)(ry * 65536.0f);
    const unsigned qz = (unsigned)(rz * 65536.0f);
    const unsigned packed = (qz << 16) | (qy & 0xffffu);

    const float v0 = vals[((size_t)b * NCLS + 0) * NPTS + n];
    const float v1 = vals[((size_t)b * NCLS + 1) * NPTS + n];
    const float4 r = make_float4(px, __uint_as_float(packed), v0, v1);

    const unsigned bin = ((unsigned)b << 16) | ((unsigned)bz << 8) | (unsigned)by;
    const unsigned slot = atomicAdd(&cursor[bin], 1u);
    if (slot < CAP) {
        rec[((size_t)bin << CAPSH) + slot] = r;
    } else {
        const unsigned o = atomicAdd(ovfcnt, 1u);
        ovf4[o] = r;
        ovfbin[o] = bin;
    }
}

// ---------------------------------------------------------------------------
// Pass 2: one block per (b, z-plane P, y-tile T). Gather the 34 contributing
// row-bins (planes P-1,P x rows RY*T-1..RY*T+15), accumulate into a 32 KB
// LDS tile with LDS atomics, stream out coalesced float4 (full coverage ->
// no global zero-init of d_out needed).
// ---------------------------------------------------------------------------
__global__ __launch_bounds__(512) void k_region(const float4* __restrict__ rec,
                                                const unsigned* __restrict__ cursor,
                                                const float4* __restrict__ ovf4,
                                                const unsigned* __restrict__ ovfbin,
                                                const unsigned* __restrict__ ovfcnt,
                                                float* __restrict__ out)
{
    __shared__ float acc[NCLS * RY * BOX];      // 32 KB
    __shared__ unsigned s_bin[NBMETA];
    __shared__ unsigned s_len[NBMETA];
    __shared__ unsigned s_pfx[NBMETA + 1];

    const int tid = threadIdx.x;
    const int bid = blockIdx.x;
    const int b = bid >> 12;
    const int P = (bid >> 4) & 255;             // owned z-plane
    const int T = bid & 15;                     // owned y-tile (rows RY*T..RY*T+15)

    // zero tile: 8192 floats = 2048 float4 / 512 threads = 4 each
    {
        float4* a4 = (float4*)acc;
        #pragma unroll
        for (int i = 0; i < 4; ++i)
            a4[i * 512 + tid] = make_float4(0.f, 0.f, 0.f, 0.f);
    }

    // metadata: j in [0,34): zsrc = P-1 + (j>=17), row y0 = RY*T-1 + (j%17)
    if (tid < NBMETA) {
        const int j = tid;
        const int zsrc = P - 1 + (j >= 17 ? 1 : 0);
        const int y0 = RY * T - 1 + (j >= 17 ? j - 17 : j);
        unsigned bin = 0, len = 0;
        if (zsrc >= 0 && y0 >= 0 && y0 < BOX) {
            bin = ((unsigned)b << 16) | ((unsigned)zsrc << 8) | (unsigned)y0;
            len = cursor[bin];
            if (len > CAP) len = CAP;
        }
        s_bin[j] = bin;
        s_len[j] = len;
    }
    __syncthreads();

    // wave-parallel exclusive scan of s_len (first wave only)
    if (tid < 64) {
        const unsigned own = (tid < NBMETA) ? s_len[tid] : 0u;
        unsigned v = own;
        #pragma unroll
        for (int off = 1; off < 64; off <<= 1) {
            const unsigned t = __shfl_up(v, off, 64);
            if (tid >= off) v += t;
        }
        if (tid < NBMETA) s_pfx[tid] = v - own;
        if (tid == NBMETA - 1) s_pfx[NBMETA] = v;
    }
    __syncthreads();

    const int R = (int)s_pfx[NBMETA];
    for (int r = tid; r < R; r += 512) {
        // binary search: lo with s_pfx[lo] <= r < s_pfx[lo+1]
        int lo = 0, hi = NBMETA - 1;
        while (lo < hi) {
            const int mid = (lo + hi + 1) >> 1;
            if ((int)s_pfx[mid] <= r) lo = mid; else hi = mid - 1;
        }
        const size_t idx = ((size_t)s_bin[lo] << CAPSH) + (unsigned)(r - (int)s_pfx[lo]);
        const float4 q = rec[idx];

        const unsigned pk = __float_as_uint(q.y);
        const float ry = (float)(pk & 0xffffu) * (1.0f / 65536.0f);
        const float rz = (float)(pk >> 16) * (1.0f / 65536.0f);
        const float fx = floorf(q.x);
        const float rx = q.x - fx;
        const int ix = (int)fx;

        // lo>=17 -> record's base plane == P -> dz=0 corner weight (1-rz)
        const float wz = (lo >= 17) ? (1.0f - rz) : rz;
        const int yy0 = (lo >= 17 ? lo - 17 : lo) - 1;     // tile row for dy=0

        #pragma unroll
        for (int dy = 0; dy < 2; ++dy) {
            const int yy = yy0 + dy;
            if ((unsigned)yy < RY) {                        // excludes y==256 too
                const float wzy = wz * (dy ? ry : 1.0f - ry);
                #pragma unroll
                for (int dx = 0; dx < 2; ++dx) {
                    const int x = ix + dx;
                    if (x < BOX) {                          // excludes x==256
                        const float w = wzy * (dx ? rx : 1.0f - rx);
                        const int li = yy * BOX + x;
                        atomicAdd(&acc[li], w * q.z);
                        atomicAdd(&acc[RY * BOX + li], w * q.w);
                    }
                }
            }
        }
    }

    // overflow records (empty for this input; kept for correctness)
    const int oc = (int)*ovfcnt;
    for (int r = tid; r < oc; r += 512) {
        const unsigned bin = ovfbin[r];
        if ((int)(bin >> 16) != b) continue;
        const int bz = (int)((bin >> 8) & 255u);
        if (bz != P && bz != P - 1) continue;
        const int by = (int)(bin & 255u);
        const int yy0 = by - RY * T;
        if (yy0 < -1 || yy0 > RY - 1) continue;

        const float4 q = ovf4[r];
        const unsigned pk = __float_as_uint(q.y);
        const float ry = (float)(pk & 0xffffu) * (1.0f / 65536.0f);
        const float rz = (float)(pk >> 16) * (1.0f / 65536.0f);
        const float fx = floorf(q.x);
        const float rx = q.x - fx;
        const int ix = (int)fx;
        const float wz = (bz == P) ? (1.0f - rz) : rz;

        for (int dy = 0; dy < 2; ++dy) {
            const int yy = yy0 + dy;
            if ((unsigned)yy < RY) {
                const float wzy = wz * (dy ? ry : 1.0f - ry);
                for (int dx = 0; dx < 2; ++dx) {
                    const int x = ix + dx;
                    if (x < BOX) {
                        const float w = wzy * (dx ? rx : 1.0f - rx);
                        const int li = yy * BOX + x;
                        atomicAdd(&acc[li], w * q.z);
                        atomicAdd(&acc[RY * BOX + li], w * q.w);
                    }
                }
            }
        }
    }
    __syncthreads();

    // stream tile out: [b][c][P][RY*T..RY*T+15][:] — coalesced float4
    #pragma unroll
    for (int c = 0; c < NCLS; ++c) {
        const size_t o4base = (size_t)((b * NCLS + c) * BOX + P) * (BOX * BOX / 4)
                              + (size_t)T * (RY * BOX / 4);
        float4* o4 = (float4*)out;
        const float4* a4 = (const float4*)(acc + c * RY * BOX);
        #pragma unroll
        for (int i = 0; i < 2; ++i)
            o4[o4base + i * 512 + tid] = a4[i * 512 + tid];
    }
}

// ---------------------------------------------------------------------------
// Fallback: plain global-atomic scatter (only if ws too small).
// ---------------------------------------------------------------------------
__global__ __launch_bounds__(256) void cic_scatter_kernel(
    const float* __restrict__ points, const float* __restrict__ values,
    float* __restrict__ out)
{
    const int tid = blockIdx.x * blockDim.x + threadIdx.x;
    if (tid >= BATCH * NPTS) return;
    const int b = tid >> 18, n = tid & (NPTS - 1);
    const float* pp = points + ((size_t)b * NPTS + n) * 3;
    const float px = (pp[0] + 0.5f) * BOX, py = (pp[1] + 0.5f) * BOX, pz = (pp[2] + 0.5f) * BOX;
    const float fx = floorf(px), fy = floorf(py), fz = floorf(pz);
    const float rx = px - fx, ry = py - fy, rz = pz - fz;
    const int ix = (int)fx, iy = (int)fy, iz = (int)fz;
    const float v0 = values[((size_t)b * NCLS + 0) * NPTS + n];
    const float v1 = values[((size_t)b * NCLS + 1) * NPTS + n];
    const float wx[2] = {1.f - rx, rx}, wy[2] = {1.f - ry, ry}, wz[2] = {1.f - rz, rz};
    float* out0 = out + ((size_t)b * NCLS + 0) * (size_t)VOL;
    float* out1 = out + ((size_t)b * NCLS + 1) * (size_t)VOL;
    for (int dz = 0; dz < 2; ++dz) {
        const int z = iz + dz; if (z >= BOX) continue;
        for (int dy = 0; dy < 2; ++dy) {
            const int y = iy + dy; if (y >= BOX) continue;
            const float wzy = wz[dz] * wy[dy];
            const int rowbase = (z * BOX + y) * BOX;
            for (int dx = 0; dx < 2; ++dx) {
                const int x = ix + dx; if (x >= BOX) continue;
                atomicAdd(out0 + rowbase + x, wzy * wx[dx] * v0);
                atomicAdd(out1 + rowbase + x, wzy * wx[dx] * v1);
            }
        }
    }
}

extern "C" void kernel_launch(void* const* d_in, const int* in_sizes, int n_in,
                              void* d_out, int out_size, void* d_ws, size_t ws_size,
                              hipStream_t stream) {
    const float* points = (const float*)d_in[0];   // [B, N, 3]
    const float* values = (const float*)d_in[1];   // [B, C, N]
    float* out = (float*)d_out;                    // [B, C, 256,256,256]

    // ws layout (16B-aligned blocks)
    const size_t CUR_OFF  = 0;                                   // NBINS u32
    const size_t OVFC_OFF = (size_t)NBINS * 4;                   // 1 u32 (+pad)
    const size_t REC_OFF  = OVFC_OFF + 256;                      // NBINS*CAP float4
    const size_t OVF4_OFF = REC_OFF + (size_t)NBINS * CAP * 16;
    const size_t OVFB_OFF = OVF4_OFF + (size_t)BATCH * NPTS * 16;
    const size_t WS_NEED  = OVFB_OFF + (size_t)BATCH * NPTS * 4;

    if (ws_size < WS_NEED) {
        hipMemsetAsync(out, 0, (size_t)out_size * sizeof(float), stream);
        cic_scatter_kernel<<<(BATCH * NPTS) / 256, 256, 0, stream>>>(points, values, out);
        return;
    }

    char* ws = (char*)d_ws;
    unsigned* cursor = (unsigned*)(ws + CUR_OFF);
    unsigned* ovfcnt = (unsigned*)(ws + OVFC_OFF);
    float4*   rec    = (float4*)(ws + REC_OFF);
    float4*   ovf4   = (float4*)(ws + OVF4_OFF);
    unsigned* ovfbin = (unsigned*)(ws + OVFB_OFF);

    // zero cursors + overflow counter
    hipMemsetAsync(ws, 0, OVFC_OFF + 256, stream);

    k_place<<<(BATCH * NPTS) / 256, 256, 0, stream>>>(points, values, cursor,
                                                      rec, ovf4, ovfbin, ovfcnt);
    k_region<<<NREG, 512, 0, stream>>>(rec, cursor, ovf4, ovfbin, ovfcnt, out);
}